// Round 3
// baseline (141.813 us; speedup 1.0000x reference)
//
#include <hip/hip_runtime.h>
#include <hip/hip_bf16.h>

// FixedChannelDP via Toeplitz-GEMM on bf16 MFMA 32x32x16.
// y[p,n] = sum_{k=0}^{512} h[k] x[p,n-k]  ('full' conv), out fp32 [2,NOUT,2].
//
// Round 3: persistent-block DOUBLE-BUFFERED TILE PIPELINE (breaks the
// stage->compute->write phase convoy that pinned rounds 0-2 at ~49 us):
//   - grid = 256 (1 block/CU), 8 waves, BLOCK_OUT = 8192 per pol.
//   - per tile: issue next tile's 20 float4 global loads into regs BEFORE
//     compute (HBM latency hidden under 34x256 cyc of MFMA); after compute,
//     vvert+ds_write into the other LDS buffer; ONE barrier per tile.
//   - h table staged to LDS once per block => inner loop is lgkm-only, so
//     in-flight global loads/stores are never drained inside compute.
//   - 513th (512-sample) tail handled by block 0 as a cheap mini-tile.
//
// Mapping per wave (strip = wave, b in [0,34)):
//   D[r][c] += sum_k A_b[r][k] * B_b[k][c],  n = N0 + strip*1024 + 32r + c
//   A_b[r][k] = x[n + k + 16 - 16b]                (8 contig -> ds_read_b128)
//   B_b[k][c] = h[16b + c - k - 16] (0 if OOB)     -> tap covered exactly once
// h table: hh[tab][R][j] = h[R-24-j]; row read at R = 16b + cc - 8*half + 8;
// rows >= 544 are all-zero (prefetch-safe).  re-part uses xi*(-hi) via v_xor.

#define NSAMP 4194304
#define LTAPS 513
#define NOUT  (NSAMP + LTAPS - 1)   // 4194816

#define BLK       512
#define WAVE_OUT  1024                  // one 32x32 D-tile strip per wave
#define BLOCK_OUT 8192                  // per pol (8 strips x 8 waves)
#define HALO      512
#define XELEMS    (BLOCK_OUT + HALO + 16)   // 8720
#define NB        34
#define HROWS     592                   // >= 584 so b=NB prefetch is in-bounds (zero rows)
#define GRID      256
#define NT        513                   // 512 full tiles + 1 mini tile (512 outputs)
#define XEL_MINI  1552                  // mini tile stages e in [0,1552)
#define SITER     5                     // ceil(XELEMS / (BLK*4))

typedef __attribute__((ext_vector_type(8)))  short short8;
typedef __attribute__((ext_vector_type(4)))  short short4v;
typedef __attribute__((ext_vector_type(4)))  int   int4v;
typedef __attribute__((ext_vector_type(16))) float float16v;

// XOR swizzle, zero space: folds element bits [6:8] into [3:5]. Bijective in
// each 64-elem block, preserves 8-elem (16 B) units.
__device__ __forceinline__ int xswz(int e) { return e ^ (((e >> 6) & 7) << 3); }
#define XSZ XELEMS

__device__ __forceinline__ short f2b(float f) {
    __bf16 b = (__bf16)f;
    return __builtin_bit_cast(short, b);
}

__global__ __launch_bounds__(BLK)
void build_h(const float* __restrict__ hr, const float* __restrict__ hi,
             short* __restrict__ hh) {
    int R = blockIdx.x * BLK + threadIdx.x;
    if (R < HROWS) {
        short8 vr, vi;
        #pragma unroll
        for (int j = 0; j < 8; ++j) {
            int idx = R - 24 - j;
            bool ok = (idx >= 0) && (idx < LTAPS);
            vr[j] = f2b(ok ? hr[idx] : 0.0f);
            vi[j] = f2b(ok ? hi[idx] : 0.0f);
        }
        *(short8*)(hh + (size_t)(0 * HROWS + R) * 8) = vr;
        *(short8*)(hh + (size_t)(1 * HROWS + R) * 8) = vi;
    }
}

#define MFMA32(A, B, C) __builtin_amdgcn_mfma_f32_32x32x16_bf16((A), (B), (C), 0, 0, 0)

__device__ __forceinline__ short8 bneg8(short8 v) {
    int4v t = __builtin_bit_cast(int4v, v);
    t ^= (int4v){(int)0x80008000, (int)0x80008000, (int)0x80008000, (int)0x80008000};
    return __builtin_bit_cast(short8, t);
}

__device__ __forceinline__ bool tile_edge(int t) { return (t == 0) || (t >= 511); }

__global__ __launch_bounds__(BLK, 2)
void fir_pipe(const float* __restrict__ txr_all, const float* __restrict__ txi_all,
              const short* __restrict__ hh, float2* __restrict__ out) {
    const int bid = blockIdx.x;
    const int tid = threadIdx.x;

    // xs: double-buffered x tiles, [buf][0]=xr p0,[1]=xi p0,[2]=xr p1,[3]=xi p1.
    __shared__ __align__(16) short xs[2][4][XSZ];     // 139,520 B
    __shared__ __align__(16) short hl[2 * HROWS * 8]; //  18,944 B  (total 158,464 B)

    // ---- h table -> LDS (once per block, flat 16B copy) ----
    {
        const int4* src = (const int4*)hh;
        int4* dst = (int4*)hl;
        #pragma unroll
        for (int it = 0; it < 3; ++it) {
            int idx = tid + it * BLK;
            if (idx < 2 * HROWS) dst[idx] = src[idx];
        }
    }

    // ---- staging register buffers (static-indexed, held across compute) ----
    float4 fr[2][SITER], fi[2][SITER];

    auto stage_load = [&](int t) {   // issue global loads for a NON-edge tile
        if (tile_edge(t)) return;
        const int N0 = t * BLOCK_OUT;
        #pragma unroll
        for (int p = 0; p < 2; ++p) {
            const float* __restrict__ xr_g = txr_all + (size_t)p * NSAMP + (N0 - HALO);
            const float* __restrict__ xi_g = txi_all + (size_t)p * NSAMP + (N0 - HALO);
            #pragma unroll
            for (int it = 0; it < SITER; ++it) {
                int e = (tid + it * BLK) * 4;
                if (e < XELEMS) {
                    fr[p][it] = *(const float4*)(xr_g + e);
                    fi[p][it] = *(const float4*)(xi_g + e);
                }
            }
        }
    };

    auto stage_write = [&](int t, int buf) {  // convert + LDS write (after loads land)
        if (!tile_edge(t)) {
            #pragma unroll
            for (int p = 0; p < 2; ++p) {
                #pragma unroll
                for (int it = 0; it < SITER; ++it) {
                    int e = (tid + it * BLK) * 4;
                    if (e < XELEMS) {
                        int ls = xswz(e);
                        float4 r = fr[p][it], i = fi[p][it];
                        short4v vr = { f2b(r.x), f2b(r.y), f2b(r.z), f2b(r.w) };
                        short4v vi = { f2b(i.x), f2b(i.y), f2b(i.z), f2b(i.w) };
                        *(short4v*)(&xs[buf][2 * p + 0][ls]) = vr;
                        *(short4v*)(&xs[buf][2 * p + 1][ls]) = vi;
                    }
                }
            }
        } else {
            // edge tiles (0, 511, 512): slow scalar-clamped staging, done inline
            const int N0  = t * BLOCK_OUT;
            const int xel = (t == NT - 1) ? XEL_MINI : XELEMS;
            for (int p = 0; p < 2; ++p) {
                const float* __restrict__ xr_g = txr_all + (size_t)p * NSAMP;
                const float* __restrict__ xi_g = txi_all + (size_t)p * NSAMP;
                for (int it = 0; it < SITER; ++it) {
                    int e = (tid + it * BLK) * 4;
                    if (e < xel) {
                        int g = N0 - HALO + e;
                        float r0, r1, r2, r3, i0, i1, i2, i3;
                        if (g >= 0 && g + 3 < NSAMP) {
                            float4 frv = *(const float4*)(xr_g + g);
                            float4 fiv = *(const float4*)(xi_g + g);
                            r0 = frv.x; r1 = frv.y; r2 = frv.z; r3 = frv.w;
                            i0 = fiv.x; i1 = fiv.y; i2 = fiv.z; i3 = fiv.w;
                        } else {
                            int gc0 = min(max(g + 0, 0), NSAMP - 1);
                            int gc1 = min(max(g + 1, 0), NSAMP - 1);
                            int gc2 = min(max(g + 2, 0), NSAMP - 1);
                            int gc3 = min(max(g + 3, 0), NSAMP - 1);
                            r0 = (g + 0 >= 0 && g + 0 < NSAMP) ? xr_g[gc0] : 0.0f;
                            r1 = (g + 1 >= 0 && g + 1 < NSAMP) ? xr_g[gc1] : 0.0f;
                            r2 = (g + 2 >= 0 && g + 2 < NSAMP) ? xr_g[gc2] : 0.0f;
                            r3 = (g + 3 >= 0 && g + 3 < NSAMP) ? xr_g[gc3] : 0.0f;
                            i0 = (g + 0 >= 0 && g + 0 < NSAMP) ? xi_g[gc0] : 0.0f;
                            i1 = (g + 1 >= 0 && g + 1 < NSAMP) ? xi_g[gc1] : 0.0f;
                            i2 = (g + 2 >= 0 && g + 2 < NSAMP) ? xi_g[gc2] : 0.0f;
                            i3 = (g + 3 >= 0 && g + 3 < NSAMP) ? xi_g[gc3] : 0.0f;
                        }
                        int ls = xswz(e);
                        short4v vr = { f2b(r0), f2b(r1), f2b(r2), f2b(r3) };
                        short4v vi = { f2b(i0), f2b(i1), f2b(i2), f2b(i3) };
                        *(short4v*)(&xs[buf][2 * p + 0][ls]) = vr;
                        *(short4v*)(&xs[buf][2 * p + 1][ls]) = vi;
                    }
                }
            }
        }
    };

    const int lane = tid & 63;
    const int wave = tid >> 6;
    const int cc   = lane & 31;     // A row r / B col c / D col
    const int half = lane >> 5;
    const short* hp0 = hl + (size_t)(cc - 8 * half + 8) * 8;

    auto compute_store = [&](int t, int buf) {
        const int N0 = t * BLOCK_OUT;
        const int nw = N0 + wave * WAVE_OUT;
        if (nw >= NOUT) return;       // mini-tile: strips past the end skip

        float16v zero = {0.f,0.f,0.f,0.f,0.f,0.f,0.f,0.f,0.f,0.f,0.f,0.f,0.f,0.f,0.f,0.f};
        float16v acc_re0 = zero, acc_im0 = zero, acc_re1 = zero, acc_im1 = zero;

        const int    ebase = HALO + wave * WAVE_OUT + 32 * cc + 8 * half + 16;
        const short* xb    = &xs[buf][0][0];

        // prologue: fragments for b=0 (all LDS -> lgkm-only inner loop)
        int ls0 = xswz(ebase);
        short8 fxr0 = *(const short8*)(xb + ls0);
        short8 fxi0 = *(const short8*)(xb + XSZ + ls0);
        short8 fxr1 = *(const short8*)(xb + 2 * XSZ + ls0);
        short8 fxi1 = *(const short8*)(xb + 3 * XSZ + ls0);
        short8 fhr  = *(const short8*)(hp0);
        short8 fhi  = *(const short8*)(hp0 + (size_t)HROWS * 8);

        #pragma unroll 2
        for (int b = 0; b < NB; ++b) {
            // prefetch b+1 operands (LDS) before b's MFMAs
            int en = ebase - 16 * (b + 1);
            en = en < 0 ? 0 : en;     // b=NB-1: clamp (values unused)
            int lsn = xswz(en);
            short8 nxr0 = *(const short8*)(xb + lsn);
            short8 nxi0 = *(const short8*)(xb + XSZ + lsn);
            short8 nxr1 = *(const short8*)(xb + 2 * XSZ + lsn);
            short8 nxi1 = *(const short8*)(xb + 3 * XSZ + lsn);
            const short* hn = hp0 + (size_t)(16 * (b + 1)) * 8;
            short8 nhr = *(const short8*)(hn);
            short8 nhi = *(const short8*)(hn + (size_t)HROWS * 8);

            short8 fnhi = bneg8(fhi);   // re-part: xi * (-hi)
            acc_re0 = MFMA32(fxr0, fhr,  acc_re0);
            acc_im0 = MFMA32(fxi0, fhr,  acc_im0);
            acc_re1 = MFMA32(fxr1, fhr,  acc_re1);
            acc_im1 = MFMA32(fxi1, fhr,  acc_im1);
            acc_re0 = MFMA32(fxi0, fnhi, acc_re0);
            acc_im0 = MFMA32(fxr0, fhi,  acc_im0);
            acc_re1 = MFMA32(fxi1, fnhi, acc_re1);
            acc_im1 = MFMA32(fxr1, fhi,  acc_im1);

            fxr0 = nxr0; fxi0 = nxi0; fxr1 = nxr1; fxi1 = nxi1;
            fhr  = nhr;  fhi  = nhi;
        }

        // epilogue: D col = cc, row = (reg&3) + 8*(reg>>2) + 4*half
        float2* __restrict__ op0 = out;
        float2* __restrict__ op1 = out + (size_t)NOUT;
        #pragma unroll
        for (int v = 0; v < 16; ++v) {
            int row = (v & 3) + 8 * (v >> 2) + 4 * half;
            int n = nw + 32 * row + cc;
            if (n < NOUT) {
                op0[n] = make_float2(acc_re0[v], acc_im0[v]);
                op1[n] = make_float2(acc_re1[v], acc_im1[v]);
            }
        }
    };

    // ---- tile pipeline:  tiles t = bid, bid+256, (block 0 also 512) ----
    stage_load(bid);
    stage_write(bid, 0);
    __syncthreads();

    int cur = 0;
    for (int t = bid; t < NT; t += GRID) {
        int tn = t + GRID;
        if (tn < NT) stage_load(tn);      // HBM latency hides under compute(t)
        compute_store(t, cur);            // lgkm-only; stores fire-and-forget
        if (tn < NT) {
            stage_write(tn, cur ^ 1);     // waits only for the staged loads
            __syncthreads();
        }
        cur ^= 1;
    }
}

extern "C" void kernel_launch(void* const* d_in, const int* in_sizes, int n_in,
                              void* d_out, int out_size, void* d_ws, size_t ws_size,
                              hipStream_t stream) {
    const float* txr = (const float*)d_in[0];
    const float* txi = (const float*)d_in[1];
    const float* hr  = (const float*)d_in[2];
    const float* hi  = (const float*)d_in[3];
    float2* out = (float2*)d_out;
    short* hh = (short*)d_ws;   // 2 * 592 * 8 bf16 ≈ 19 KB

    build_h<<<dim3((HROWS + BLK - 1) / BLK), BLK, 0, stream>>>(hr, hi, hh);

    fir_pipe<<<dim3(GRID), BLK, 0, stream>>>(txr, txi, hh, out);
}

// Round 4
// 139.339 us; speedup vs baseline: 1.0178x; 1.0178x over previous
//
#include <hip/hip_runtime.h>
#include <hip/hip_bf16.h>

// FixedChannelDP via Toeplitz-GEMM on bf16 MFMA 32x32x16.
// y[p,n] = sum_{k=0}^{512} h[k] x[p,n-k]  ('full' conv), out fp32 [2,NOUT,2].
//
// Round 4: persistent blocks + staging INTERLEAVED INTO THE K-LOOP.
// Rounds 0-3 all ran phase-serial (stage -> compute -> write ~= sum of floors
// ~49 us; round 3's monolithic reg-prefetch was sunk by the compiler --
// VGPR=108 vs ~190 needed). Fix: fold next-tile staging into the fully
// unrolled 34-step K-loop as a ring: slot j (2 float4 loads) issues at step
// 2j, its cvt+ds_write lands at step 2j+8 (~2000 cyc horizon, <=5 slots /
// 40 VGPRs live). One raw s_barrier per tile (lgkmcnt(0) only -- no vmcnt(0)
// drain); epilogue stores after the barrier so they overlap the next tile.
//
// Mapping per wave (strip = wave, b in [0,34)):
//   D[r][c] += sum_k A_b[r][k] * B_b[k][c],  n = N0 + wave*1024 + 32r + c
//   A_b[r][k] = x[n + k + 16 - 16b]                (8 contig -> ds_read_b128)
//   B_b[k][c] = h[16b + c - k - 16] (0 if OOB)     -> tap covered exactly once
// h table: hh[tab][R][j] = h[R-24-j]; row read at R = 16b + cc - 8*half + 8;
// rows >= 544 all-zero.  re-part uses xi*(-hi) via one v_xor on h.

#define NSAMP 4194304
#define LTAPS 513
#define NOUT  (NSAMP + LTAPS - 1)   // 4194816

#define BLK       512
#define WAVE_OUT  1024                  // one 32x32 D-tile strip per wave
#define BLOCK_OUT 8192                  // per pol (8 waves, both pols each)
#define HALO      512
#define XELEMS    (BLOCK_OUT + HALO + 16)   // 8720
#define NB        34
#define HROWS     592
#define GRID      256
#define NT        513                   // 512 full tiles + 1 mini tile (512 outs)
#define SITER     5                     // ceil(XELEMS / (BLK*4))

typedef __attribute__((ext_vector_type(8)))  short short8;
typedef __attribute__((ext_vector_type(4)))  short short4v;
typedef __attribute__((ext_vector_type(4)))  int   int4v;
typedef __attribute__((ext_vector_type(16))) float float16v;

// XOR swizzle, zero space: folds element bits [6:8] into [3:5]. Bijective in
// each 64-elem block, preserves 8-elem (16 B) units.
__device__ __forceinline__ int xswz(int e) { return e ^ (((e >> 6) & 7) << 3); }
#define XSZ XELEMS

__device__ __forceinline__ short f2b(float f) {
    __bf16 b = (__bf16)f;
    return __builtin_bit_cast(short, b);
}

__global__ __launch_bounds__(BLK)
void build_h(const float* __restrict__ hr, const float* __restrict__ hi,
             short* __restrict__ hh) {
    int R = blockIdx.x * BLK + threadIdx.x;
    if (R < HROWS) {
        short8 vr, vi;
        #pragma unroll
        for (int j = 0; j < 8; ++j) {
            int idx = R - 24 - j;
            bool ok = (idx >= 0) && (idx < LTAPS);
            vr[j] = f2b(ok ? hr[idx] : 0.0f);
            vi[j] = f2b(ok ? hi[idx] : 0.0f);
        }
        *(short8*)(hh + (size_t)(0 * HROWS + R) * 8) = vr;
        *(short8*)(hh + (size_t)(1 * HROWS + R) * 8) = vi;
    }
}

#define MFMA32(A, B, C) __builtin_amdgcn_mfma_f32_32x32x16_bf16((A), (B), (C), 0, 0, 0)

__device__ __forceinline__ short8 bneg8(short8 v) {
    int4v t = __builtin_bit_cast(int4v, v);
    t ^= (int4v){(int)0x80008000, (int)0x80008000, (int)0x80008000, (int)0x80008000};
    return __builtin_bit_cast(short8, t);
}

__device__ __forceinline__ bool tile_edge(int t) { return (t == 0) || (t >= 511); }

__global__ __launch_bounds__(BLK, 2)
void fir_pipe(const float* __restrict__ txr_all, const float* __restrict__ txi_all,
              const short* __restrict__ hh, float2* __restrict__ out) {
    const int bid = blockIdx.x;
    const int tid = threadIdx.x;

    // xs: double-buffered x tiles, [buf][0]=xr p0,[1]=xi p0,[2]=xr p1,[3]=xi p1.
    __shared__ __align__(16) short xs[2][4][XSZ];     // 139,520 B
    __shared__ __align__(16) short hl[2 * HROWS * 8]; //  18,944 B (tot 158,464 B)

    // ---- h table -> LDS (once per block, flat 16B copies) ----
    {
        const int4* src = (const int4*)hh;
        int4* dst = (int4*)hl;
        #pragma unroll
        for (int it = 0; it < 3; ++it) {
            int idx = tid + it * BLK;
            if (idx < 2 * HROWS) dst[idx] = src[idx];
        }
    }

    // generic (clamped) serial tile stage — prologue + edge tiles only
    auto stage_tile = [&](int t, int buf) {
        const int N0 = t * BLOCK_OUT;
        short* xnb = &xs[buf][0][0];
        for (int p = 0; p < 2; ++p) {
            const float* __restrict__ xr_g = txr_all + (size_t)p * NSAMP;
            const float* __restrict__ xi_g = txi_all + (size_t)p * NSAMP;
            for (int it = 0; it < SITER; ++it) {
                int e = (tid + it * BLK) * 4;
                if (e < XELEMS) {
                    int g = N0 - HALO + e;
                    float r0, r1, r2, r3, i0, i1, i2, i3;
                    if (g >= 0 && g + 3 < NSAMP) {
                        float4 frv = *(const float4*)(xr_g + g);
                        float4 fiv = *(const float4*)(xi_g + g);
                        r0 = frv.x; r1 = frv.y; r2 = frv.z; r3 = frv.w;
                        i0 = fiv.x; i1 = fiv.y; i2 = fiv.z; i3 = fiv.w;
                    } else {
                        int gc0 = min(max(g + 0, 0), NSAMP - 1);
                        int gc1 = min(max(g + 1, 0), NSAMP - 1);
                        int gc2 = min(max(g + 2, 0), NSAMP - 1);
                        int gc3 = min(max(g + 3, 0), NSAMP - 1);
                        r0 = (g + 0 >= 0 && g + 0 < NSAMP) ? xr_g[gc0] : 0.0f;
                        r1 = (g + 1 >= 0 && g + 1 < NSAMP) ? xr_g[gc1] : 0.0f;
                        r2 = (g + 2 >= 0 && g + 2 < NSAMP) ? xr_g[gc2] : 0.0f;
                        r3 = (g + 3 >= 0 && g + 3 < NSAMP) ? xr_g[gc3] : 0.0f;
                        i0 = (g + 0 >= 0 && g + 0 < NSAMP) ? xi_g[gc0] : 0.0f;
                        i1 = (g + 1 >= 0 && g + 1 < NSAMP) ? xi_g[gc1] : 0.0f;
                        i2 = (g + 2 >= 0 && g + 2 < NSAMP) ? xi_g[gc2] : 0.0f;
                        i3 = (g + 3 >= 0 && g + 3 < NSAMP) ? xi_g[gc3] : 0.0f;
                    }
                    int ls = xswz(e);
                    short4v vr = { f2b(r0), f2b(r1), f2b(r2), f2b(r3) };
                    short4v vi = { f2b(i0), f2b(i1), f2b(i2), f2b(i3) };
                    *(short4v*)(xnb + (size_t)(2 * p + 0) * XSZ + ls) = vr;
                    *(short4v*)(xnb + (size_t)(2 * p + 1) * XSZ + ls) = vi;
                }
            }
        }
    };

    const int lane = tid & 63;
    const int wave = tid >> 6;
    const int cc   = lane & 31;     // A row r / B col c / D col
    const int half = lane >> 5;
    const short* hp0  = hl + (size_t)(cc - 8 * half + 8) * 8;
    const int   ebase = HALO + wave * WAVE_OUT + 32 * cc + 8 * half + 16;

    // ---- pipeline fill: stage own first tile ----
    stage_tile(bid, 0);
    asm volatile("s_waitcnt lgkmcnt(0)" ::: "memory");
    __builtin_amdgcn_s_barrier();
    __builtin_amdgcn_sched_barrier(0);

    int cur = 0;
    for (int t = bid; t < NT; t += GRID) {
        const int  tn = t + GRID;
        const bool do_stage = (tn < NT) && !tile_edge(tn);
        const int  N0 = t * BLOCK_OUT;
        const int  nw = N0 + wave * WAVE_OUT;
        const bool did = (nw < NOUT);          // false only for mini-tile strips

        float16v zero = {0.f,0.f,0.f,0.f,0.f,0.f,0.f,0.f,0.f,0.f,0.f,0.f,0.f,0.f,0.f,0.f};
        float16v acc_re0 = zero, acc_im0 = zero, acc_re1 = zero, acc_im1 = zero;

        if (did) {
            const short* xb  = &xs[cur][0][0];
            short*       xnb = &xs[cur ^ 1][0][0];
            const int    sg  = tn * BLOCK_OUT - HALO;   // next-tile staging base
            float4 sr[10], si[10];                      // staging ring (static idx)

            #pragma unroll
            for (int b = 0; b < NB; ++b) {
                // -- staging ring: issue slot j at step 2j (j = 0..9) --
                if ((b & 1) == 0 && b < 20) {
                    if (do_stage) {
                        const int j  = b >> 1;
                        const int p  = (j >= SITER) ? 1 : 0;
                        const int it = j - p * SITER;
                        const int e  = (tid + it * BLK) * 4;
                        if (e < XELEMS) {
                            const float* xr_g = txr_all + (size_t)p * NSAMP + sg + e;
                            const float* xi_g = txi_all + (size_t)p * NSAMP + sg + e;
                            sr[j] = *(const float4*)xr_g;
                            si[j] = *(const float4*)xi_g;
                        }
                    }
                }
                // -- staging ring: cvt + ds_write slot j at step 2j+8 --
                if ((b & 1) == 0 && b >= 8 && b < 28) {
                    if (do_stage) {
                        const int j  = (b - 8) >> 1;
                        const int p  = (j >= SITER) ? 1 : 0;
                        const int it = j - p * SITER;
                        const int e  = (tid + it * BLK) * 4;
                        if (e < XELEMS) {
                            int ls = xswz(e);
                            float4 r = sr[j], i = si[j];
                            short4v vr = { f2b(r.x), f2b(r.y), f2b(r.z), f2b(r.w) };
                            short4v vi = { f2b(i.x), f2b(i.y), f2b(i.z), f2b(i.w) };
                            *(short4v*)(xnb + (size_t)(2 * p + 0) * XSZ + ls) = vr;
                            *(short4v*)(xnb + (size_t)(2 * p + 1) * XSZ + ls) = vi;
                        }
                    }
                }

                // -- compute step b: 6 LDS b128 reads + 8 MFMAs --
                int ls = xswz(ebase - 16 * b);
                short8 fxr0 = *(const short8*)(xb + ls);
                short8 fxi0 = *(const short8*)(xb + XSZ + ls);
                short8 fxr1 = *(const short8*)(xb + 2 * XSZ + ls);
                short8 fxi1 = *(const short8*)(xb + 3 * XSZ + ls);
                const short* hp = hp0 + (size_t)(16 * b) * 8;
                short8 fhr = *(const short8*)(hp);
                short8 fhi = *(const short8*)(hp + (size_t)HROWS * 8);

                short8 fnhi = bneg8(fhi);   // re-part: xi * (-hi)
                acc_re0 = MFMA32(fxr0, fhr,  acc_re0);
                acc_im0 = MFMA32(fxi0, fhr,  acc_im0);
                acc_re1 = MFMA32(fxr1, fhr,  acc_re1);
                acc_im1 = MFMA32(fxi1, fhr,  acc_im1);
                acc_re0 = MFMA32(fxi0, fnhi, acc_re0);
                acc_im0 = MFMA32(fxr0, fhi,  acc_im0);
                acc_re1 = MFMA32(fxi1, fnhi, acc_re1);
                acc_im1 = MFMA32(fxr1, fhi,  acc_im1);
            }
        }

        // edge target tiles (511, 512): slow serial stage outside the hot loop
        if (tn < NT && tile_edge(tn)) stage_tile(tn, cur ^ 1);

        // one raw barrier per tile: LDS drain only (no vmcnt(0) store drain)
        asm volatile("s_waitcnt lgkmcnt(0)" ::: "memory");
        __builtin_amdgcn_s_barrier();
        __builtin_amdgcn_sched_barrier(0);

        // epilogue AFTER the barrier: stores drain under the next tile's work.
        if (did) {
            float2* __restrict__ op0 = out;
            float2* __restrict__ op1 = out + (size_t)NOUT;
            #pragma unroll
            for (int v = 0; v < 16; ++v) {
                int row = (v & 3) + 8 * (v >> 2) + 4 * half;
                int n = nw + 32 * row + cc;
                if (n < NOUT) {
                    op0[n] = make_float2(acc_re0[v], acc_im0[v]);
                    op1[n] = make_float2(acc_re1[v], acc_im1[v]);
                }
            }
        }
        cur ^= 1;
    }
}

extern "C" void kernel_launch(void* const* d_in, const int* in_sizes, int n_in,
                              void* d_out, int out_size, void* d_ws, size_t ws_size,
                              hipStream_t stream) {
    const float* txr = (const float*)d_in[0];
    const float* txi = (const float*)d_in[1];
    const float* hr  = (const float*)d_in[2];
    const float* hi  = (const float*)d_in[3];
    float2* out = (float2*)d_out;
    short* hh = (short*)d_ws;   // 2 * 592 * 8 bf16 ≈ 19 KB

    build_h<<<dim3((HROWS + BLK - 1) / BLK), BLK, 0, stream>>>(hr, hi, hh);

    fir_pipe<<<dim3(GRID), BLK, 0, stream>>>(txr, txi, hh, out);
}